// Round 19
// baseline (236.327 us; speedup 1.0000x reference)
//
#include <hip/hip_runtime.h>

#define DEV static __device__ __forceinline__

namespace {
constexpr int PB   = 4096;
constexpr int NPTS = 32768;
constexpr int RR   = 8;
constexpr int K    = 16;
constexpr int COUT = 128;
constexpr int NK   = NPTS * K;    // 524288
constexpr int GS1  = 8192;        // stage1 grid (4 n per block, 1 per wave)
constexpr float BN_EPS = 1e-5f;

// ws float offsets (first 1152 floats zeroed by memset each call)
constexpr int    WS_SUM1 = 0;                         // 4
constexpr int    WS_SUM3 = 68;                        // 8
constexpr int    WS_P2C  = 128;                       // 16*64 coarse BN2 partials
constexpr size_t WS_W1   = 2048;                      // NK*32 bf16
constexpr size_t WS_W2   = WS_W1 + (size_t)NK * 16;   // NK*4 f32
}

typedef __attribute__((ext_vector_type(8))) __bf16 bf16x8;
typedef __attribute__((ext_vector_type(4))) float  f32x4;

DEV int nbr_idx(int n, int j) {
    int b = n >> 12, i = n & (PB - 1);
    int o = (j < RR) ? (j - RR) : (j - RR + 1);
    return (b << 12) | ((i + o + PB) & (PB - 1));
}
DEV float wave_sum(float v) {
    #pragma unroll
    for (int off = 32; off >= 1; off >>= 1) v += __shfl_xor(v, off);
    return v;
}
DEV bf16x8 cvt8(float4 a, float4 b) {
    bf16x8 r;
    r[0] = (__bf16)a.x; r[1] = (__bf16)a.y; r[2] = (__bf16)a.z; r[3] = (__bf16)a.w;
    r[4] = (__bf16)b.x; r[5] = (__bf16)b.y; r[6] = (__bf16)b.z; r[7] = (__bf16)b.w;
    return r;
}
DEV float bflo(unsigned u) { union { unsigned x; float f; } c; c.x = u << 16; return c.f; }
DEV float bfhi(unsigned u) { union { unsigned x; float f; } c; c.x = u & 0xffff0000u; return c.f; }
DEV void wave_fence() {
    asm volatile("s_waitcnt lgkmcnt(0)" ::: "memory");
    __builtin_amdgcn_sched_barrier(0);
}

// ---------------- k_pre: BN1 sums straight from pts ----------------
__global__ __launch_bounds__(256) void k_pre(const float* __restrict__ pts,
                                             const float* __restrict__ Wp1,
                                             float* __restrict__ ws)
{
    __shared__ float red[4][4];
    const int t = threadIdx.x, w = t >> 6;
    const float wp10 = Wp1[0], wp11 = Wp1[1], wp12 = Wp1[2], wp13 = Wp1[3];
    float a[4] = {0.f, 0.f, 0.f, 0.f};
    #pragma unroll
    for (int it = 0; it < 4; ++it) {
        const int row = blockIdx.x * 1024 + it * 256 + t;
        const int n = row >> 4, j = row & 15;
        const int idxr = nbr_idx(n, j);
        const float2 pn = ((const float2*)pts)[n];
        const float2 pq = ((const float2*)pts)[idxr];
        const float tx = pq.x - pn.x, ty = pq.y - pn.y;
        const float p10 = wp10 * tx + wp11 * ty;
        const float p11 = wp12 * tx + wp13 * ty;
        a[0] += p10; a[1] += p11; a[2] += p10 * p10; a[3] += p11 * p11;
    }
    #pragma unroll
    for (int q = 0; q < 4; ++q) {
        float s = wave_sum(a[q]);
        if ((t & 63) == 0) red[w][q] = s;
    }
    __syncthreads();
    if (t < 4) atomicAdd(&ws[WS_SUM1 + t], red[0][t] + red[1][t] + red[2][t] + red[3][t]);
}

// ---------------- stage 1 (fused MFMA, 1 n/wave, grid 8192) ----------------
__global__ __launch_bounds__(256) void k_stage1(
    const float* __restrict__ pts, const float* __restrict__ feat,
    const float* __restrict__ W1, const float* __restrict__ b1,
    const float* __restrict__ Wb, const float* __restrict__ bb,
    const float* __restrict__ Wp1, const float* __restrict__ Wp2,
    const float* __restrict__ bp2, const float* __restrict__ gp,
    const float* __restrict__ bp, const float* __restrict__ W2a,
    float* __restrict__ out_trans, float* __restrict__ out_idx,
    float* __restrict__ ws)
{
    __shared__ float  es[4][16][36];
    __shared__ bf16x8 wbLds[512];
    __shared__ float  sA0[16], sA1[16], sA2[16];
    __shared__ float  red[4][64];

    const int t = threadIdx.x, w = t >> 6, l = t & 63, c0 = l & 15, jg = l >> 4;
    const int bid = blockIdx.x;
    const int n = ((bid & 7) * (GS1 / 8) + (bid >> 3)) * 4 + w;   // XCD-bijective, 1 n/wave

    for (int f = t; f < 512; f += 256) {
        const int lg = f >> 6, ll = f & 63, cc0 = ll & 15, jj = ll >> 4;
        const float4* p = (const float4*)(Wb + cc0 * 256 + lg * 32 + jj * 8);
        wbLds[f] = cvt8(p[0], p[1]);
    }
    if (t < 16) {
        float a0 = 0.f, a1 = 0.f, a2 = 0.f;
        for (int a8 = 0; a8 < 8; ++a8) {
            const int cc = a8 * 16 + t;
            a0 += Wp2[2 * cc]; a1 += Wp2[2 * cc + 1]; a2 += bp2[cc];
        }
        sA0[t] = a0; sA1[t] = a1; sA2[t] = a2;
    }

    const float invM = 1.f / (float)NK;
    const float m0 = ws[WS_SUM1 + 0] * invM, m1 = ws[WS_SUM1 + 1] * invM;
    const float q0 = ws[WS_SUM1 + 2] * invM, q1 = ws[WS_SUM1 + 3] * invM;
    const float sc1x = gp[0] * rsqrtf(q0 - m0 * m0 + BN_EPS);
    const float sc1y = gp[1] * rsqrtf(q1 - m1 * m1 + BN_EPS);
    const float sh1x = fmaf(-m0, sc1x, bp[0]), sh1y = fmaf(-m1, sc1y, bp[1]);
    const float wp10 = Wp1[0], wp11 = Wp1[1], wp12 = Wp1[2], wp13 = Wp1[3];

    const float w1cx = W1[c0 * 66], w1cy = W1[c0 * 66 + 1];
    const float b1c = b1[c0], bbc = bb[c0];
    bf16x8 w1b[2];
    #pragma unroll
    for (int kf = 0; kf < 2; ++kf) {
        const float* p = W1 + c0 * 66 + 2 + kf * 32 + jg * 8;
        const float2 v0 = *(const float2*)(p),     v1 = *(const float2*)(p + 2);
        const float2 v2 = *(const float2*)(p + 4), v3 = *(const float2*)(p + 6);
        w1b[kf] = cvt8(make_float4(v0.x, v0.y, v1.x, v1.y),
                       make_float4(v2.x, v2.y, v3.x, v3.y));
    }
    bf16x8 w2ab[2];
    #pragma unroll
    for (int tq = 0; tq < 2; ++tq) {
        const float4* p = (const float4*)(W2a + (c0 + 16 * tq) * 32 + jg * 8);
        w2ab[tq] = cvt8(p[0], p[1]);
    }

    // per-n prefetch (1 n)
    const int idxr = nbr_idx(n, c0);
    const float2 pn = ((const float2*)pts)[n];
    const float2 pq = ((const float2*)pts)[idxr];
    const float tx = pq.x - pn.x, ty = pq.y - pn.y;
    const float p10 = wp10 * tx + wp11 * ty;
    const float p11 = wp12 * tx + wp13 * ty;
    const float ph0 = fmaxf(fmaf(p10, sc1x, sh1x), 0.f);
    const float ph1 = fmaxf(fmaf(p11, sc1y, sh1y), 0.f);
    const float4* fb = (const float4*)(feat + (size_t)idxr * 64 + jg * 8);
    const bf16x8 fa0 = cvt8(fb[0], fb[1]);
    const bf16x8 fa1 = cvt8(fb[8], fb[9]);
    if (jg == 0) {
        ((float2*)out_trans)[n * 16 + c0] = make_float2(tx, ty);
        out_idx[n * 16 + c0] = (float)idxr;
    }

    __syncthreads();    // wbLds + sA ready

    // ---- P0: e-tile ----
    {
        f32x4 acc;
        #pragma unroll
        for (int r = 0; r < 4; ++r) {
            const int row = jg * 4 + r;
            const float trx  = __shfl(tx, row);
            const float tryv = __shfl(ty, row);
            acc[r] = b1c + w1cx * trx + w1cy * tryv;
        }
        acc = __builtin_amdgcn_mfma_f32_16x16x32_bf16(fa0, w1b[0], acc, 0, 0, 0);
        acc = __builtin_amdgcn_mfma_f32_16x16x32_bf16(fa1, w1b[1], acc, 0, 0, 0);
        #pragma unroll
        for (int r = 0; r < 4; ++r) es[w][jg * 4 + r][c0] = fmaxf(acc[r], 0.f);
    }
    wave_fence();

    // ---- P1: bilinear ----
    const bool hi = (jg & 1);
    const bool ih = (jg >> 1);
    {
        const float4 ef0 = *(const float4*)&es[w][c0][0];
        const float4 ef1 = *(const float4*)&es[w][c0][4];
        const float4 ef2 = *(const float4*)&es[w][c0][8];
        const float4 ef3 = *(const float4*)&es[w][c0][12];
        const float ev[16] = {ef0.x, ef0.y, ef0.z, ef0.w, ef1.x, ef1.y, ef1.z, ef1.w,
                              ef2.x, ef2.y, ef2.z, ef2.w, ef3.x, ef3.y, ef3.z, ef3.w};
        float eh[8];
        #pragma unroll
        for (int e = 0; e < 8; ++e) eh[e] = hi ? ev[8 + e] : ev[e];
        f32x4 acc2;
        #pragma unroll
        for (int r = 0; r < 4; ++r) acc2[r] = bbc;
        #pragma unroll
        for (int g = 0; g < 8; ++g) {
            const bf16x8 wg = wbLds[g * 64 + l];
            const float ei = ih ? ev[2 * g + 1] : ev[2 * g];
            bf16x8 a2;
            #pragma unroll
            for (int e = 0; e < 8; ++e) a2[e] = (__bf16)(ei * eh[e]);
            acc2 = __builtin_amdgcn_mfma_f32_16x16x32_bf16(a2, wg, acc2, 0, 0, 0);
        }
        #pragma unroll
        for (int r = 0; r < 4; ++r) es[w][jg * 4 + r][16 + c0] = acc2[r];
    }
    wave_fence();

    // ---- P2: x-frag + w1 GEMM ----
    float s10 = 0.f, s11 = 0.f, s20 = 0.f, s21 = 0.f;
    f32x4 w1a0, w1a1;
    {
        bf16x8 xa;
        if (jg < 2) {
            const float* src = &es[w][c0][16 + jg * 8];
            #pragma unroll
            for (int e = 0; e < 8; ++e) xa[e] = (__bf16)src[e];
        } else {
            const int off = (jg - 2) * 8;
            #pragma unroll
            for (int e = 0; e < 8; ++e)
                xa[e] = (__bf16)fmaf(ph0, sA0[off + e],
                                     fmaf(ph1, sA1[off + e], sA2[off + e]));
        }
        const f32x4 z4 = {0.f, 0.f, 0.f, 0.f};
        w1a0 = __builtin_amdgcn_mfma_f32_16x16x32_bf16(xa, w2ab[0], z4, 0, 0, 0);
        w1a1 = __builtin_amdgcn_mfma_f32_16x16x32_bf16(xa, w2ab[1], z4, 0, 0, 0);
        #pragma unroll
        for (int r = 0; r < 4; ++r) {
            s10 += w1a0[r]; s20 += w1a0[r] * w1a0[r];
            s11 += w1a1[r]; s21 += w1a1[r] * w1a1[r];
        }
    }
    wave_fence();   // energy reads complete before overwrite
    #pragma unroll
    for (int r = 0; r < 4; ++r) {
        es[w][jg * 4 + r][c0]      = w1a0[r];
        es[w][jg * 4 + r][16 + c0] = w1a1[r];
    }
    wave_fence();

    // ---- P3: pack w1 -> bf16, coalesced store ----
    {
        const int row = l >> 2, ch = l & 3;
        const float* src = &es[w][row][ch * 8];
        bf16x8 pk;
        #pragma unroll
        for (int e = 0; e < 8; ++e) pk[e] = (__bf16)src[e];
        reinterpret_cast<bf16x8*>(ws + WS_W1)[(size_t)(n * 16 + row) * 4 + ch] = pk;
    }

    // BN2 partials -> 16 coarse atomic slots
    #pragma unroll
    for (int off = 16; off <= 32; off <<= 1) {
        s10 += __shfl_xor(s10, off); s11 += __shfl_xor(s11, off);
        s20 += __shfl_xor(s20, off); s21 += __shfl_xor(s21, off);
    }
    if (jg == 0) {
        red[w][c0] = s10; red[w][16 + c0] = s11;
        red[w][32 + c0] = s20; red[w][48 + c0] = s21;
    }
    __syncthreads();
    if (t < 64)
        atomicAdd(&ws[WS_P2C + ((bid >> 9) & 15) * 64 + t],
                  red[0][t] + red[1][t] + red[2][t] + red[3][t]);
}

// ---------------- stage 3: coarse BN2 reduce in prologue; w1 -> w2, BN3 sums ----------------
__global__ __launch_bounds__(256) void k_stage3(
    const float* __restrict__ g2a, const float* __restrict__ b2a,
    const float* __restrict__ W2b, float* __restrict__ ws)
{
    __shared__ float s2l[64];
    __shared__ float sc2s[32], sh2s[32], w2bs[128];
    __shared__ float red[4][8];
    const int t = threadIdx.x, w = t >> 6, l = t & 63;

    if (t < 64) {                      // reduce 16 coarse slots (1 KB, L2-hot)
        const float* P = ws + WS_P2C;
        float s = 0.f;
        #pragma unroll
        for (int r = 0; r < 16; ++r) s += P[r * 64 + t];
        s2l[t] = s;
    }
    if (t < 128) w2bs[t] = W2b[t];
    __syncthreads();
    if (t < 32) {
        const float invM = 1.f / (float)NK;
        const float m = s2l[t] * invM, q = s2l[32 + t] * invM;
        const float sc = g2a[t] * rsqrtf(q - m * m + BN_EPS);
        sc2s[t] = sc; sh2s[t] = fmaf(-m, sc, b2a[t]);
    }
    __syncthreads();

    const size_t row = (size_t)blockIdx.x * 256 + t;
    const uint4* w1u = reinterpret_cast<const uint4*>(ws + WS_W1) + row * 4;
    float h[32];
    #pragma unroll
    for (int i = 0; i < 4; ++i) {
        const uint4 u = w1u[i];
        h[i*8+0] = bflo(u.x); h[i*8+1] = bfhi(u.x);
        h[i*8+2] = bflo(u.y); h[i*8+3] = bfhi(u.y);
        h[i*8+4] = bflo(u.z); h[i*8+5] = bfhi(u.z);
        h[i*8+6] = bflo(u.w); h[i*8+7] = bfhi(u.w);
    }
    float acc[4] = {0.f, 0.f, 0.f, 0.f};
    #pragma unroll
    for (int q = 0; q < 32; ++q) {
        const float hv = fmaxf(fmaf(h[q], sc2s[q], sh2s[q]), 0.f);
        #pragma unroll
        for (int p = 0; p < 4; ++p) acc[p] = fmaf(w2bs[p * 32 + q], hv, acc[p]);
    }
    ((float4*)(ws + WS_W2))[row] = make_float4(acc[0], acc[1], acc[2], acc[3]);

    float r8[8] = {acc[0], acc[1], acc[2], acc[3],
                   acc[0]*acc[0], acc[1]*acc[1], acc[2]*acc[2], acc[3]*acc[3]};
    #pragma unroll
    for (int i = 0; i < 8; ++i) r8[i] = wave_sum(r8[i]);
    if (l == 0) {
        #pragma unroll
        for (int i = 0; i < 8; ++i) red[w][i] = r8[i];
    }
    __syncthreads();
    if (t < 8) atomicAdd(&ws[WS_SUM3 + t], red[0][t] + red[1][t] + red[2][t] + red[3][t]);
}

// ---- stage 4 (MFMA; COUT quarter-split: 2 s-groups per block for 16 n; grid 8192) ----
__global__ __launch_bounds__(256) void k_stage4(
    const float* __restrict__ feat, const float* __restrict__ Wp1,
    const float* __restrict__ Wp2, const float* __restrict__ bp2,
    const float* __restrict__ W2c, const float* __restrict__ b2c,
    const float* __restrict__ W3, const float* __restrict__ b3,
    const float* __restrict__ gp, const float* __restrict__ bp,
    const float* __restrict__ g2b, const float* __restrict__ b2b,
    const float* __restrict__ out_trans, const float* __restrict__ ws,
    float* __restrict__ out)
{
    __shared__ bf16x8 w3lds[256];       // quarter of W3 (4 KB)
    __shared__ float4 pA[8], pB[8], pC[8];
    __shared__ float4 w2c4[16];
    __shared__ float  b2cs[16];

    const int t = threadIdx.x, w = t >> 6, l = t & 63, c0 = l & 15, jg = l >> 4;
    const int bid = blockIdx.x;
    const int grp = (bid & 7) * 1024 + (bid >> 3);   // XCD-bijective over 8192
    const int ng  = grp >> 2;
    const int sq  = (grp & 3) * 2;
    const int n0  = ng * 16 + w * 4;

    for (int f = t; f < 256; f += 256) {
        const int sl = f >> 7, kf = (f >> 6) & 1, l2 = f & 63;
        const float4* p = (const float4*)(W3 + (size_t)(16 * (sq + sl) + (l2 & 15)) * 64
                                          + kf * 32 + (l2 >> 4) * 8);
        w3lds[f] = cvt8(p[0], p[1]);
    }
    if (t < 8) {
        const int sl = t >> 2, cc = 16 * (sq + sl) + (t & 3) * 4;
        pA[t] = make_float4(Wp2[2*cc], Wp2[2*cc+2], Wp2[2*cc+4], Wp2[2*cc+6]);
        pB[t] = make_float4(Wp2[2*cc+1], Wp2[2*cc+3], Wp2[2*cc+5], Wp2[2*cc+7]);
        pC[t] = make_float4(bp2[cc] + b3[cc], bp2[cc+1] + b3[cc+1],
                            bp2[cc+2] + b3[cc+2], bp2[cc+3] + b3[cc+3]);
    }
    if (t < 16) {
        w2c4[t] = make_float4(W2c[4*t], W2c[4*t+1], W2c[4*t+2], W2c[4*t+3]);
        b2cs[t] = b2c[t];
    }

    const float invM = 1.f / (float)NK;
    const float m0 = ws[WS_SUM1 + 0] * invM, m1 = ws[WS_SUM1 + 1] * invM;
    const float q0 = ws[WS_SUM1 + 2] * invM, q1 = ws[WS_SUM1 + 3] * invM;
    const float sc1x = gp[0] * rsqrtf(q0 - m0 * m0 + BN_EPS);
    const float sc1y = gp[1] * rsqrtf(q1 - m1 * m1 + BN_EPS);
    const float sh1x = fmaf(-m0, sc1x, bp[0]), sh1y = fmaf(-m1, sc1y, bp[1]);
    const float wp10 = Wp1[0], wp11 = Wp1[1], wp12 = Wp1[2], wp13 = Wp1[3];
    float sc3[4], sh3[4];
    #pragma unroll
    for (int p = 0; p < 4; ++p) {
        const float m = ws[WS_SUM3 + p] * invM, q = ws[WS_SUM3 + 4 + p] * invM;
        sc3[p] = g2b[p] * rsqrtf(q - m * m + BN_EPS);
        sh3[p] = fmaf(-m, sc3[p], b2b[p]);
    }

    int idxr[4]; float2 trv[4]; float4 qv[4];
    bf16x8 fa0[4], fa1[4];
    #pragma unroll
    for (int nn = 0; nn < 4; ++nn) {
        const int n = n0 + nn;
        idxr[nn] = nbr_idx(n, c0);
        const float4* fb = (const float4*)(feat + (size_t)idxr[nn] * 64 + jg * 8);
        fa0[nn] = cvt8(fb[0], fb[1]);
        fa1[nn] = cvt8(fb[8], fb[9]);
        trv[nn] = ((const float2*)out_trans)[n * 16 + c0];
        qv[nn]  = ((const float4*)(ws + WS_W2))[n * 16 + c0];
    }
    __syncthreads();

    #pragma unroll
    for (int nn = 0; nn < 4; ++nn) {
        const int n = n0 + nn;
        const float p10 = wp10 * trv[nn].x + wp11 * trv[nn].y;
        const float p11 = wp12 * trv[nn].x + wp13 * trv[nn].y;
        const float ph0 = fmaxf(fmaf(p10, sc1x, sh1x), 0.f);
        const float ph1 = fmaxf(fmaf(p11, sc1y, sh1y), 0.f);
        const float h0 = fmaxf(fmaf(qv[nn].x, sc3[0], sh3[0]), 0.f);
        const float h1 = fmaxf(fmaf(qv[nn].y, sc3[1], sh3[1]), 0.f);
        const float h2 = fmaxf(fmaf(qv[nn].z, sc3[2], sh3[2]), 0.f);
        const float h3 = fmaxf(fmaf(qv[nn].w, sc3[3], sh3[3]), 0.f);
        float wsm[4];
        #pragma unroll
        for (int r = 0; r < 4; ++r) {
            const int c = jg * 4 + r;
            const float4 wc = w2c4[c];
            const float lgv = b2cs[c] + wc.x * h0 + wc.y * h1 + wc.z * h2 + wc.w * h3;
            // |lgv| <= ~1.2 analytically (validated R8): exp without max-subtraction
            const float ex = __expf(lgv);
            float ss = ex;
            #pragma unroll
            for (int off = 1; off <= 8; off <<= 1) ss += __shfl_xor(ss, off);
            wsm[r] = ex / ss;
        }
        float* ob = out + (size_t)(n * 16 + c0) * COUT;
        #pragma unroll
        for (int sl = 0; sl < 2; ++sl) {
            const float4 a4 = pA[sl * 4 + jg], b4 = pB[sl * 4 + jg], c4 = pC[sl * 4 + jg];
            f32x4 ci;
            ci[0] = fmaf(ph0, a4.x, fmaf(ph1, b4.x, c4.x));
            ci[1] = fmaf(ph0, a4.y, fmaf(ph1, b4.y, c4.y));
            ci[2] = fmaf(ph0, a4.z, fmaf(ph1, b4.z, c4.z));
            ci[3] = fmaf(ph0, a4.w, fmaf(ph1, b4.w, c4.w));
            ci = __builtin_amdgcn_mfma_f32_16x16x32_bf16(w3lds[sl * 128 + l],      fa0[nn], ci, 0, 0, 0);
            ci = __builtin_amdgcn_mfma_f32_16x16x32_bf16(w3lds[sl * 128 + 64 + l], fa1[nn], ci, 0, 0, 0);
            f32x4 o4;
            o4[0] = ci[0] * wsm[0]; o4[1] = ci[1] * wsm[1];
            o4[2] = ci[2] * wsm[2]; o4[3] = ci[3] * wsm[3];
            __builtin_nontemporal_store(o4, (f32x4*)(ob + 16 * (sq + sl) + jg * 4));
        }
    }
}

extern "C" void kernel_launch(void* const* d_in, const int* in_sizes, int n_in,
                              void* d_out, int out_size, void* d_ws, size_t ws_size,
                              hipStream_t stream)
{
    const float* pts  = (const float*)d_in[0];
    const float* feat = (const float*)d_in[1];
    const float* W1   = (const float*)d_in[2];
    const float* b1   = (const float*)d_in[3];
    const float* Wb   = (const float*)d_in[4];
    const float* bb   = (const float*)d_in[5];
    const float* Wp1  = (const float*)d_in[6];
    const float* gp   = (const float*)d_in[7];
    const float* bp   = (const float*)d_in[8];
    const float* Wp2  = (const float*)d_in[9];
    const float* bp2  = (const float*)d_in[10];
    const float* W2a  = (const float*)d_in[11];
    const float* g2a  = (const float*)d_in[12];
    const float* b2a  = (const float*)d_in[13];
    const float* W2b  = (const float*)d_in[14];
    const float* g2b  = (const float*)d_in[15];
    const float* b2b  = (const float*)d_in[16];
    const float* W2c  = (const float*)d_in[17];
    const float* b2c  = (const float*)d_in[18];
    const float* W3   = (const float*)d_in[19];
    const float* b3   = (const float*)d_in[20];

    float* out       = (float*)d_out;
    float* out_trans = out + (size_t)NK * COUT;
    float* out_idx   = out_trans + (size_t)NK * 2;
    float* ws        = (float*)d_ws;

    hipMemsetAsync(ws, 0, 1152 * sizeof(float), stream);  // SUM1/SUM3/P2C
    k_pre<<<512, 256, 0, stream>>>(pts, Wp1, ws);
    k_stage1<<<GS1, 256, 0, stream>>>(pts, feat, W1, b1, Wb, bb, Wp1, Wp2, bp2,
                                      gp, bp, W2a, out_trans, out_idx, ws);
    k_stage3<<<2048, 256, 0, stream>>>(g2a, b2a, W2b, ws);
    k_stage4<<<8192, 256, 0, stream>>>(feat, Wp1, Wp2, bp2, W2c, b2c, W3, b3,
                                       gp, bp, g2b, b2b, out_trans, ws, out);
}

// Round 20
// 210.606 us; speedup vs baseline: 1.1221x; 1.1221x over previous
//
#include <hip/hip_runtime.h>

#define DEV static __device__ __forceinline__

namespace {
constexpr int PB   = 4096;
constexpr int NPTS = 32768;
constexpr int RR   = 8;
constexpr int K    = 16;
constexpr int COUT = 128;
constexpr int NK   = NPTS * K;    // 524288
constexpr int GS1  = 4096;        // stage1 grid (8 n per block, 2 per wave)
constexpr float BN_EPS = 1e-5f;

// ws float offsets (first 1152 floats zeroed by memset each call)
constexpr int    WS_SUM1 = 0;                         // 4
constexpr int    WS_SUM3 = 68;                        // 8
constexpr int    WS_P2C  = 128;                       // 16*64 coarse BN2 partials
constexpr size_t WS_W1   = 2048;                      // NK*32 bf16
constexpr size_t WS_W2   = WS_W1 + (size_t)NK * 16;   // NK*4 f32
}

typedef __attribute__((ext_vector_type(8))) __bf16 bf16x8;
typedef __attribute__((ext_vector_type(4))) float  f32x4;

DEV int nbr_idx(int n, int j) {
    int b = n >> 12, i = n & (PB - 1);
    int o = (j < RR) ? (j - RR) : (j - RR + 1);
    return (b << 12) | ((i + o + PB) & (PB - 1));
}
DEV float wave_sum(float v) {
    #pragma unroll
    for (int off = 32; off >= 1; off >>= 1) v += __shfl_xor(v, off);
    return v;
}
DEV bf16x8 cvt8(float4 a, float4 b) {
    bf16x8 r;
    r[0] = (__bf16)a.x; r[1] = (__bf16)a.y; r[2] = (__bf16)a.z; r[3] = (__bf16)a.w;
    r[4] = (__bf16)b.x; r[5] = (__bf16)b.y; r[6] = (__bf16)b.z; r[7] = (__bf16)b.w;
    return r;
}
DEV float bflo(unsigned u) { union { unsigned x; float f; } c; c.x = u << 16; return c.f; }
DEV float bfhi(unsigned u) { union { unsigned x; float f; } c; c.x = u & 0xffff0000u; return c.f; }
DEV void wave_fence() {
    asm volatile("s_waitcnt lgkmcnt(0)" ::: "memory");
    __builtin_amdgcn_sched_barrier(0);
}

// ---------------- k_pre: BN1 sums straight from pts ----------------
__global__ __launch_bounds__(256) void k_pre(const float* __restrict__ pts,
                                             const float* __restrict__ Wp1,
                                             float* __restrict__ ws)
{
    __shared__ float red[4][4];
    const int t = threadIdx.x, w = t >> 6;
    const float wp10 = Wp1[0], wp11 = Wp1[1], wp12 = Wp1[2], wp13 = Wp1[3];
    float a[4] = {0.f, 0.f, 0.f, 0.f};
    #pragma unroll
    for (int it = 0; it < 4; ++it) {
        const int row = blockIdx.x * 1024 + it * 256 + t;
        const int n = row >> 4, j = row & 15;
        const int idxr = nbr_idx(n, j);
        const float2 pn = ((const float2*)pts)[n];
        const float2 pq = ((const float2*)pts)[idxr];
        const float tx = pq.x - pn.x, ty = pq.y - pn.y;
        const float p10 = wp10 * tx + wp11 * ty;
        const float p11 = wp12 * tx + wp13 * ty;
        a[0] += p10; a[1] += p11; a[2] += p10 * p10; a[3] += p11 * p11;
    }
    #pragma unroll
    for (int q = 0; q < 4; ++q) {
        float s = wave_sum(a[q]);
        if ((t & 63) == 0) red[w][q] = s;
    }
    __syncthreads();
    if (t < 4) atomicAdd(&ws[WS_SUM1 + t], red[0][t] + red[1][t] + red[2][t] + red[3][t]);
}

// ---------------- stage 1 (fused MFMA, 2 n/wave; BN2 -> 16 coarse atomic slots) ----------------
__global__ __launch_bounds__(256) void k_stage1(
    const float* __restrict__ pts, const float* __restrict__ feat,
    const float* __restrict__ W1, const float* __restrict__ b1,
    const float* __restrict__ Wb, const float* __restrict__ bb,
    const float* __restrict__ Wp1, const float* __restrict__ Wp2,
    const float* __restrict__ bp2, const float* __restrict__ gp,
    const float* __restrict__ bp, const float* __restrict__ W2a,
    float* __restrict__ out_trans, float* __restrict__ out_idx,
    float* __restrict__ ws)
{
    __shared__ float  es[4][2][16][36];
    __shared__ bf16x8 wbLds[512];
    __shared__ float  sA0[16], sA1[16], sA2[16];
    __shared__ float  red[4][64];

    const int t = threadIdx.x, w = t >> 6, l = t & 63, c0 = l & 15, jg = l >> 4;
    const int bid = blockIdx.x;
    const int n0 = ((bid & 7) * (GS1 / 8) + (bid >> 3)) * 8 + w * 2;  // XCD-bijective

    for (int f = t; f < 512; f += 256) {
        const int lg = f >> 6, ll = f & 63, cc0 = ll & 15, jj = ll >> 4;
        const float4* p = (const float4*)(Wb + cc0 * 256 + lg * 32 + jj * 8);
        wbLds[f] = cvt8(p[0], p[1]);
    }
    if (t < 16) {
        float a0 = 0.f, a1 = 0.f, a2 = 0.f;
        for (int a8 = 0; a8 < 8; ++a8) {
            const int cc = a8 * 16 + t;
            a0 += Wp2[2 * cc]; a1 += Wp2[2 * cc + 1]; a2 += bp2[cc];
        }
        sA0[t] = a0; sA1[t] = a1; sA2[t] = a2;
    }

    const float invM = 1.f / (float)NK;
    const float m0 = ws[WS_SUM1 + 0] * invM, m1 = ws[WS_SUM1 + 1] * invM;
    const float q0 = ws[WS_SUM1 + 2] * invM, q1 = ws[WS_SUM1 + 3] * invM;
    const float sc1x = gp[0] * rsqrtf(q0 - m0 * m0 + BN_EPS);
    const float sc1y = gp[1] * rsqrtf(q1 - m1 * m1 + BN_EPS);
    const float sh1x = fmaf(-m0, sc1x, bp[0]), sh1y = fmaf(-m1, sc1y, bp[1]);
    const float wp10 = Wp1[0], wp11 = Wp1[1], wp12 = Wp1[2], wp13 = Wp1[3];

    const float w1cx = W1[c0 * 66], w1cy = W1[c0 * 66 + 1];
    const float b1c = b1[c0], bbc = bb[c0];
    bf16x8 w1b[2];
    #pragma unroll
    for (int kf = 0; kf < 2; ++kf) {
        const float* p = W1 + c0 * 66 + 2 + kf * 32 + jg * 8;
        const float2 v0 = *(const float2*)(p),     v1 = *(const float2*)(p + 2);
        const float2 v2 = *(const float2*)(p + 4), v3 = *(const float2*)(p + 6);
        w1b[kf] = cvt8(make_float4(v0.x, v0.y, v1.x, v1.y),
                       make_float4(v2.x, v2.y, v3.x, v3.y));
    }
    bf16x8 w2ab[2];
    #pragma unroll
    for (int tq = 0; tq < 2; ++tq) {
        const float4* p = (const float4*)(W2a + (c0 + 16 * tq) * 32 + jg * 8);
        w2ab[tq] = cvt8(p[0], p[1]);
    }

    float txv[2], tyv[2], ph0v[2], ph1v[2];
    bf16x8 fa0[2], fa1[2];
    #pragma unroll
    for (int nn = 0; nn < 2; ++nn) {
        const int n = n0 + nn;
        const int idxr = nbr_idx(n, c0);
        const float2 pn = ((const float2*)pts)[n];
        const float2 pq = ((const float2*)pts)[idxr];
        txv[nn] = pq.x - pn.x; tyv[nn] = pq.y - pn.y;
        const float p10 = wp10 * txv[nn] + wp11 * tyv[nn];
        const float p11 = wp12 * txv[nn] + wp13 * tyv[nn];
        ph0v[nn] = fmaxf(fmaf(p10, sc1x, sh1x), 0.f);
        ph1v[nn] = fmaxf(fmaf(p11, sc1y, sh1y), 0.f);
        const float4* fb = (const float4*)(feat + (size_t)idxr * 64 + jg * 8);
        fa0[nn] = cvt8(fb[0], fb[1]);
        fa1[nn] = cvt8(fb[8], fb[9]);
        if (jg == 0) {
            ((float2*)out_trans)[n * 16 + c0] = make_float2(txv[nn], tyv[nn]);
            out_idx[n * 16 + c0] = (float)idxr;
        }
    }

    __syncthreads();

    #pragma unroll
    for (int nn = 0; nn < 2; ++nn) {
        f32x4 acc;
        #pragma unroll
        for (int r = 0; r < 4; ++r) {
            const int row = jg * 4 + r;
            const float trx  = __shfl(txv[nn], row);
            const float tryv = __shfl(tyv[nn], row);
            acc[r] = b1c + w1cx * trx + w1cy * tryv;
        }
        acc = __builtin_amdgcn_mfma_f32_16x16x32_bf16(fa0[nn], w1b[0], acc, 0, 0, 0);
        acc = __builtin_amdgcn_mfma_f32_16x16x32_bf16(fa1[nn], w1b[1], acc, 0, 0, 0);
        #pragma unroll
        for (int r = 0; r < 4; ++r) es[w][nn][jg * 4 + r][c0] = fmaxf(acc[r], 0.f);
    }
    wave_fence();

    const bool hi = (jg & 1);
    const bool ih = (jg >> 1);
    #pragma unroll
    for (int nn = 0; nn < 2; ++nn) {
        const float4 ef0 = *(const float4*)&es[w][nn][c0][0];
        const float4 ef1 = *(const float4*)&es[w][nn][c0][4];
        const float4 ef2 = *(const float4*)&es[w][nn][c0][8];
        const float4 ef3 = *(const float4*)&es[w][nn][c0][12];
        const float ev[16] = {ef0.x, ef0.y, ef0.z, ef0.w, ef1.x, ef1.y, ef1.z, ef1.w,
                              ef2.x, ef2.y, ef2.z, ef2.w, ef3.x, ef3.y, ef3.z, ef3.w};
        float eh[8];
        #pragma unroll
        for (int e = 0; e < 8; ++e) eh[e] = hi ? ev[8 + e] : ev[e];
        f32x4 acc2;
        #pragma unroll
        for (int r = 0; r < 4; ++r) acc2[r] = bbc;
        #pragma unroll
        for (int g = 0; g < 8; ++g) {
            const bf16x8 wg = wbLds[g * 64 + l];
            const float ei = ih ? ev[2 * g + 1] : ev[2 * g];
            bf16x8 a2;
            #pragma unroll
            for (int e = 0; e < 8; ++e) a2[e] = (__bf16)(ei * eh[e]);
            acc2 = __builtin_amdgcn_mfma_f32_16x16x32_bf16(a2, wg, acc2, 0, 0, 0);
        }
        #pragma unroll
        for (int r = 0; r < 4; ++r) es[w][nn][jg * 4 + r][16 + c0] = acc2[r];
    }
    wave_fence();

    float s10 = 0.f, s11 = 0.f, s20 = 0.f, s21 = 0.f;
    f32x4 w1a0[2], w1a1[2];
    #pragma unroll
    for (int nn = 0; nn < 2; ++nn) {
        bf16x8 xa;
        if (jg < 2) {
            const float* src = &es[w][nn][c0][16 + jg * 8];
            #pragma unroll
            for (int e = 0; e < 8; ++e) xa[e] = (__bf16)src[e];
        } else {
            const int off = (jg - 2) * 8;
            #pragma unroll
            for (int e = 0; e < 8; ++e)
                xa[e] = (__bf16)fmaf(ph0v[nn], sA0[off + e],
                                     fmaf(ph1v[nn], sA1[off + e], sA2[off + e]));
        }
        const f32x4 z4 = {0.f, 0.f, 0.f, 0.f};
        w1a0[nn] = __builtin_amdgcn_mfma_f32_16x16x32_bf16(xa, w2ab[0], z4, 0, 0, 0);
        w1a1[nn] = __builtin_amdgcn_mfma_f32_16x16x32_bf16(xa, w2ab[1], z4, 0, 0, 0);
        #pragma unroll
        for (int r = 0; r < 4; ++r) {
            s10 += w1a0[nn][r]; s20 += w1a0[nn][r] * w1a0[nn][r];
            s11 += w1a1[nn][r]; s21 += w1a1[nn][r] * w1a1[nn][r];
        }
    }
    wave_fence();
    #pragma unroll
    for (int nn = 0; nn < 2; ++nn) {
        #pragma unroll
        for (int r = 0; r < 4; ++r) {
            es[w][nn][jg * 4 + r][c0]      = w1a0[nn][r];
            es[w][nn][jg * 4 + r][16 + c0] = w1a1[nn][r];
        }
    }
    wave_fence();

    #pragma unroll
    for (int nn = 0; nn < 2; ++nn) {
        const int row = l >> 2, ch = l & 3;
        const float* src = &es[w][nn][row][ch * 8];
        bf16x8 pk;
        #pragma unroll
        for (int e = 0; e < 8; ++e) pk[e] = (__bf16)src[e];
        reinterpret_cast<bf16x8*>(ws + WS_W1)[(size_t)((n0 + nn) * 16 + row) * 4 + ch] = pk;
    }

    #pragma unroll
    for (int off = 16; off <= 32; off <<= 1) {
        s10 += __shfl_xor(s10, off); s11 += __shfl_xor(s11, off);
        s20 += __shfl_xor(s20, off); s21 += __shfl_xor(s21, off);
    }
    if (jg == 0) {
        red[w][c0] = s10; red[w][16 + c0] = s11;
        red[w][32 + c0] = s20; red[w][48 + c0] = s21;
    }
    __syncthreads();
    if (t < 64)
        atomicAdd(&ws[WS_P2C + ((bid >> 8) & 15) * 64 + t],
                  red[0][t] + red[1][t] + red[2][t] + red[3][t]);
}

// ---------------- stage 3: coarse BN2 reduce in prologue; w1 -> w2, BN3 sums ----------------
__global__ __launch_bounds__(256) void k_stage3(
    const float* __restrict__ g2a, const float* __restrict__ b2a,
    const float* __restrict__ W2b, float* __restrict__ ws)
{
    __shared__ float s2l[64];
    __shared__ float sc2s[32], sh2s[32], w2bs[128];
    __shared__ float red[4][8];
    const int t = threadIdx.x, w = t >> 6, l = t & 63;

    if (t < 64) {                      // reduce 16 coarse slots (1 KB, L2-hot)
        const float* P = ws + WS_P2C;
        float s = 0.f;
        #pragma unroll
        for (int r = 0; r < 16; ++r) s += P[r * 64 + t];
        s2l[t] = s;
    }
    if (t < 128) w2bs[t] = W2b[t];
    __syncthreads();
    if (t < 32) {
        const float invM = 1.f / (float)NK;
        const float m = s2l[t] * invM, q = s2l[32 + t] * invM;
        const float sc = g2a[t] * rsqrtf(q - m * m + BN_EPS);
        sc2s[t] = sc; sh2s[t] = fmaf(-m, sc, b2a[t]);
    }
    __syncthreads();

    const size_t row = (size_t)blockIdx.x * 256 + t;
    const uint4* w1u = reinterpret_cast<const uint4*>(ws + WS_W1) + row * 4;
    float h[32];
    #pragma unroll
    for (int i = 0; i < 4; ++i) {
        const uint4 u = w1u[i];
        h[i*8+0] = bflo(u.x); h[i*8+1] = bfhi(u.x);
        h[i*8+2] = bflo(u.y); h[i*8+3] = bfhi(u.y);
        h[i*8+4] = bflo(u.z); h[i*8+5] = bfhi(u.z);
        h[i*8+6] = bflo(u.w); h[i*8+7] = bfhi(u.w);
    }
    float acc[4] = {0.f, 0.f, 0.f, 0.f};
    #pragma unroll
    for (int q = 0; q < 32; ++q) {
        const float hv = fmaxf(fmaf(h[q], sc2s[q], sh2s[q]), 0.f);
        #pragma unroll
        for (int p = 0; p < 4; ++p) acc[p] = fmaf(w2bs[p * 32 + q], hv, acc[p]);
    }
    ((float4*)(ws + WS_W2))[row] = make_float4(acc[0], acc[1], acc[2], acc[3]);

    float r8[8] = {acc[0], acc[1], acc[2], acc[3],
                   acc[0]*acc[0], acc[1]*acc[1], acc[2]*acc[2], acc[3]*acc[3]};
    #pragma unroll
    for (int i = 0; i < 8; ++i) r8[i] = wave_sum(r8[i]);
    if (l == 0) {
        #pragma unroll
        for (int i = 0; i < 8; ++i) red[w][i] = r8[i];
    }
    __syncthreads();
    if (t < 8) atomicAdd(&ws[WS_SUM3 + t], red[0][t] + red[1][t] + red[2][t] + red[3][t]);
}

// ---- stage 4 (MFMA; COUT quarter-split: 2 s-groups per block for 16 n; grid 8192) ----
__global__ __launch_bounds__(256) void k_stage4(
    const float* __restrict__ feat, const float* __restrict__ Wp1,
    const float* __restrict__ Wp2, const float* __restrict__ bp2,
    const float* __restrict__ W2c, const float* __restrict__ b2c,
    const float* __restrict__ W3, const float* __restrict__ b3,
    const float* __restrict__ gp, const float* __restrict__ bp,
    const float* __restrict__ g2b, const float* __restrict__ b2b,
    const float* __restrict__ out_trans, const float* __restrict__ ws,
    float* __restrict__ out)
{
    __shared__ bf16x8 w3lds[256];       // quarter of W3 (4 KB)
    __shared__ float4 pA[8], pB[8], pC[8];
    __shared__ float4 w2c4[16];
    __shared__ float  b2cs[16];

    const int t = threadIdx.x, w = t >> 6, l = t & 63, c0 = l & 15, jg = l >> 4;
    const int bid = blockIdx.x;
    const int grp = (bid & 7) * 1024 + (bid >> 3);   // XCD-bijective over 8192
    const int ng  = grp >> 2;
    const int sq  = (grp & 3) * 2;
    const int n0  = ng * 16 + w * 4;

    for (int f = t; f < 256; f += 256) {
        const int sl = f >> 7, kf = (f >> 6) & 1, l2 = f & 63;
        const float4* p = (const float4*)(W3 + (size_t)(16 * (sq + sl) + (l2 & 15)) * 64
                                          + kf * 32 + (l2 >> 4) * 8);
        w3lds[f] = cvt8(p[0], p[1]);
    }
    if (t < 8) {
        const int sl = t >> 2, cc = 16 * (sq + sl) + (t & 3) * 4;
        pA[t] = make_float4(Wp2[2*cc], Wp2[2*cc+2], Wp2[2*cc+4], Wp2[2*cc+6]);
        pB[t] = make_float4(Wp2[2*cc+1], Wp2[2*cc+3], Wp2[2*cc+5], Wp2[2*cc+7]);
        pC[t] = make_float4(bp2[cc] + b3[cc], bp2[cc+1] + b3[cc+1],
                            bp2[cc+2] + b3[cc+2], bp2[cc+3] + b3[cc+3]);
    }
    if (t < 16) {
        w2c4[t] = make_float4(W2c[4*t], W2c[4*t+1], W2c[4*t+2], W2c[4*t+3]);
        b2cs[t] = b2c[t];
    }

    const float invM = 1.f / (float)NK;
    const float m0 = ws[WS_SUM1 + 0] * invM, m1 = ws[WS_SUM1 + 1] * invM;
    const float q0 = ws[WS_SUM1 + 2] * invM, q1 = ws[WS_SUM1 + 3] * invM;
    const float sc1x = gp[0] * rsqrtf(q0 - m0 * m0 + BN_EPS);
    const float sc1y = gp[1] * rsqrtf(q1 - m1 * m1 + BN_EPS);
    const float sh1x = fmaf(-m0, sc1x, bp[0]), sh1y = fmaf(-m1, sc1y, bp[1]);
    const float wp10 = Wp1[0], wp11 = Wp1[1], wp12 = Wp1[2], wp13 = Wp1[3];
    float sc3[4], sh3[4];
    #pragma unroll
    for (int p = 0; p < 4; ++p) {
        const float m = ws[WS_SUM3 + p] * invM, q = ws[WS_SUM3 + 4 + p] * invM;
        sc3[p] = g2b[p] * rsqrtf(q - m * m + BN_EPS);
        sh3[p] = fmaf(-m, sc3[p], b2b[p]);
    }

    int idxr[4]; float2 trv[4]; float4 qv[4];
    bf16x8 fa0[4], fa1[4];
    #pragma unroll
    for (int nn = 0; nn < 4; ++nn) {
        const int n = n0 + nn;
        idxr[nn] = nbr_idx(n, c0);
        const float4* fb = (const float4*)(feat + (size_t)idxr[nn] * 64 + jg * 8);
        fa0[nn] = cvt8(fb[0], fb[1]);
        fa1[nn] = cvt8(fb[8], fb[9]);
        trv[nn] = ((const float2*)out_trans)[n * 16 + c0];
        qv[nn]  = ((const float4*)(ws + WS_W2))[n * 16 + c0];
    }
    __syncthreads();

    #pragma unroll
    for (int nn = 0; nn < 4; ++nn) {
        const int n = n0 + nn;
        const float p10 = wp10 * trv[nn].x + wp11 * trv[nn].y;
        const float p11 = wp12 * trv[nn].x + wp13 * trv[nn].y;
        const float ph0 = fmaxf(fmaf(p10, sc1x, sh1x), 0.f);
        const float ph1 = fmaxf(fmaf(p11, sc1y, sh1y), 0.f);
        const float h0 = fmaxf(fmaf(qv[nn].x, sc3[0], sh3[0]), 0.f);
        const float h1 = fmaxf(fmaf(qv[nn].y, sc3[1], sh3[1]), 0.f);
        const float h2 = fmaxf(fmaf(qv[nn].z, sc3[2], sh3[2]), 0.f);
        const float h3 = fmaxf(fmaf(qv[nn].w, sc3[3], sh3[3]), 0.f);
        float wsm[4];
        #pragma unroll
        for (int r = 0; r < 4; ++r) {
            const int c = jg * 4 + r;
            const float4 wc = w2c4[c];
            const float lgv = b2cs[c] + wc.x * h0 + wc.y * h1 + wc.z * h2 + wc.w * h3;
            // |lgv| <= ~1.2 analytically (validated R8): exp without max-subtraction
            const float ex = __expf(lgv);
            float ss = ex;
            #pragma unroll
            for (int off = 1; off <= 8; off <<= 1) ss += __shfl_xor(ss, off);
            wsm[r] = ex / ss;
        }
        float* ob = out + (size_t)(n * 16 + c0) * COUT;
        #pragma unroll
        for (int sl = 0; sl < 2; ++sl) {
            const float4 a4 = pA[sl * 4 + jg], b4 = pB[sl * 4 + jg], c4 = pC[sl * 4 + jg];
            f32x4 ci;
            ci[0] = fmaf(ph0, a4.x, fmaf(ph1, b4.x, c4.x));
            ci[1] = fmaf(ph0, a4.y, fmaf(ph1, b4.y, c4.y));
            ci[2] = fmaf(ph0, a4.z, fmaf(ph1, b4.z, c4.z));
            ci[3] = fmaf(ph0, a4.w, fmaf(ph1, b4.w, c4.w));
            ci = __builtin_amdgcn_mfma_f32_16x16x32_bf16(w3lds[sl * 128 + l],      fa0[nn], ci, 0, 0, 0);
            ci = __builtin_amdgcn_mfma_f32_16x16x32_bf16(w3lds[sl * 128 + 64 + l], fa1[nn], ci, 0, 0, 0);
            f32x4 o4;
            o4[0] = ci[0] * wsm[0]; o4[1] = ci[1] * wsm[1];
            o4[2] = ci[2] * wsm[2]; o4[3] = ci[3] * wsm[3];
            __builtin_nontemporal_store(o4, (f32x4*)(ob + 16 * (sq + sl) + jg * 4));
        }
    }
}

extern "C" void kernel_launch(void* const* d_in, const int* in_sizes, int n_in,
                              void* d_out, int out_size, void* d_ws, size_t ws_size,
                              hipStream_t stream)
{
    const float* pts  = (const float*)d_in[0];
    const float* feat = (const float*)d_in[1];
    const float* W1   = (const float*)d_in[2];
    const float* b1   = (const float*)d_in[3];
    const float* Wb   = (const float*)d_in[4];
    const float* bb   = (const float*)d_in[5];
    const float* Wp1  = (const float*)d_in[6];
    const float* gp   = (const float*)d_in[7];
    const float* bp   = (const float*)d_in[8];
    const float* Wp2  = (const float*)d_in[9];
    const float* bp2  = (const float*)d_in[10];
    const float* W2a  = (const float*)d_in[11];
    const float* g2a  = (const float*)d_in[12];
    const float* b2a  = (const float*)d_in[13];
    const float* W2b  = (const float*)d_in[14];
    const float* g2b  = (const float*)d_in[15];
    const float* b2b  = (const float*)d_in[16];
    const float* W2c  = (const float*)d_in[17];
    const float* b2c  = (const float*)d_in[18];
    const float* W3   = (const float*)d_in[19];
    const float* b3   = (const float*)d_in[20];

    float* out       = (float*)d_out;
    float* out_trans = out + (size_t)NK * COUT;
    float* out_idx   = out_trans + (size_t)NK * 2;
    float* ws        = (float*)d_ws;

    hipMemsetAsync(ws, 0, 1152 * sizeof(float), stream);  // SUM1/SUM3/P2C
    k_pre<<<512, 256, 0, stream>>>(pts, Wp1, ws);
    k_stage1<<<GS1, 256, 0, stream>>>(pts, feat, W1, b1, Wb, bb, Wp1, Wp2, bp2,
                                      gp, bp, W2a, out_trans, out_idx, ws);
    k_stage3<<<2048, 256, 0, stream>>>(g2a, b2a, W2b, ws);
    k_stage4<<<8192, 256, 0, stream>>>(feat, Wp1, Wp2, bp2, W2c, b2c, W3, b3,
                                       gp, bp, g2b, b2b, out_trans, ws, out);
}